// Round 12
// baseline (654.259 us; speedup 1.0000x reference)
//
#include <hip/hip_runtime.h>

#define BQ   2
#define QQ   65536
#define HID  256
#define ENC  64
#define NPIX 4096          // 64*64
#define KCONV 576          // ENC*9
#define NROW (BQ*QQ*4)     // 524288

using bf16x8 = __bf16 __attribute__((ext_vector_type(8)));
using bf16x4 = __bf16 __attribute__((ext_vector_type(4)));
using f32x4  = float  __attribute__((ext_vector_type(4)));
using f32x16 = float  __attribute__((ext_vector_type(16)));

__device__ __forceinline__ unsigned short f2bf(float f){
  unsigned u = __float_as_uint(f);
  u = (u + 0x7fffu + ((u >> 16) & 1u)) >> 16;
  return (unsigned short)u;
}
// unpack 2 packed bf16 (one uint) -> 2 floats (low ushort = first elem)
__device__ __forceinline__ float2 bf2x(unsigned u){
  float2 r;
  r.x = __uint_as_float(u << 16);
  r.y = __uint_as_float(u & 0xffff0000u);
  return r;
}

// sin(2*pi*r) via v_fract + v_sin (ISA: v_sin input in revolutions).
__device__ __forceinline__ float sin_rev(float r){
  float f, s;
  asm("v_fract_f32 %0, %1" : "=v"(f) : "v"(r));
  asm("v_sin_f32 %0, %1"   : "=v"(s) : "v"(f));
  return s;
}

// byte offset of bf16 element (row,col) in a [64][256] bf16 LDS tile,
// XOR-swizzled at 16B granularity (bank-balanced for all access patterns).
__device__ __forceinline__ int xaddr(int row, int col){
  return row*512 + ((((col >> 3) ^ (row & 7)) << 4) | ((col & 7) << 1));
}

// ---------------- prep: weight conversion ---------------------------------
__global__ void prep_kernel(const float* coef_w, const float* freq_w,
                            const float* w0, const float* w1,
                            const float* w2, const float* w3,
                            const float* wo,
                            unsigned short* Wcat, unsigned short* Wmlp,
                            unsigned short* wo_pad){
  int idx = blockIdx.x*256 + threadIdx.x;
  if (idx < 512*KCONV){
    int n = idx / KCONV, k = idx % KCONV;
    int j = k >> 6, cin = k & 63;
    const float* src = (n < 256) ? coef_w : freq_w;
    Wcat[idx] = f2bf(src[(n & 255)*KCONV + cin*9 + j]);
    return;
  }
  int i2 = idx - 512*KCONV;
  if (i2 < 4*65536){
    const float* wl = (i2 < 65536) ? w0 : (i2 < 131072) ? w1
                     : (i2 < 196608) ? w2 : w3;
    Wmlp[i2] = f2bf(wl[i2 & 65535]);
    return;
  }
  int i3 = i2 - 4*65536;
  if (i3 < 16*256){
    int c = i3 >> 8, k = i3 & 255;
    wo_pad[i3] = (c < 3) ? f2bf(wo[c*256 + k]) : (unsigned short)0;
  }
}

// ---------------- enc conv: inp -> fpad bf16 [B][66][66][64] (padded) -----
__global__ __launch_bounds__(256)
void enc_conv_kernel(const float* inp, const float* enc_w, const float* enc_b,
                     unsigned short* fpad){
  __shared__ float wl[ENC*27];
  __shared__ float bl2[ENC];
  int t = threadIdx.x;
  for (int i = t; i < ENC*27; i += 256) wl[i] = enc_w[i];
  if (t < ENC) bl2[t] = enc_b[t];
  __syncthreads();
  int px  = blockIdx.x*32 + (t >> 3);   // 0..8191
  int oc0 = (t & 7)*8;                  // 8 output channels per thread
  int b = px >> 12, yx = px & 4095;
  int y = yx >> 6, x = yx & 63;
  float v[27];
  #pragma unroll
  for (int c = 0; c < 3; c++)
    #pragma unroll
    for (int dy = 0; dy < 3; dy++)
      #pragma unroll
      for (int dx = 0; dx < 3; dx++){
        int yy = y + dy - 1, xx = x + dx - 1;
        v[c*9 + dy*3 + dx] = (yy >= 0 && yy < 64 && xx >= 0 && xx < 64)
                             ? inp[(b*3 + c)*NPIX + yy*64 + xx] : 0.f;
      }
  bf16x8 o;
  #pragma unroll
  for (int oc = 0; oc < 8; oc++){
    float acc = bl2[oc0 + oc];
    #pragma unroll
    for (int k = 0; k < 27; k++) acc += wl[(oc0 + oc)*27 + k]*v[k];
    o[oc] = (__bf16)acc;
  }
  *(bf16x8*)(fpad + ((b*66 + y + 1)*66 + x + 1)*64 + oc0) = o;
}

// ---------------- conv GEMM: coef/freq -> bf16 pixel-major -----------------
__global__ __launch_bounds__(256)
void conv_gemm_kernel(const unsigned short* fpad, const unsigned short* Wcat,
                      const float* coef_b, const float* freq_b,
                      unsigned short* coefB, unsigned short* freqB){
  int wave = threadIdx.x >> 6, lane = threadIdx.x & 63;
  int l16 = lane & 15, g = lane >> 4;
  int tile = blockIdx.x*4 + wave;           // 16384 = 512 pt * 32 nt
  int nt = tile & 31, pt = tile >> 5;
  int gp = pt*16 + l16;                     // pixel handled by this lane
  int b = gp >> 12, y = (gp >> 6) & 63, x = gp & 63;
  const unsigned short* fbase = fpad + ((b*66 + y)*66 + x)*64;
  const unsigned short* Wp = Wcat + (nt*16 + l16)*KCONV + g*8;
  f32x4 acc;
  {
    const float* bsrc = (nt < 16) ? coef_b : freq_b;
    float4 b4 = *(const float4*)(bsrc + ((nt*16) & 255) + g*4);
    acc[0] = b4.x; acc[1] = b4.y; acc[2] = b4.z; acc[3] = b4.w;
  }
  #pragma unroll
  for (int kk = 0; kk < 18; kk++){
    int j = kk >> 1, dy = j/3, dx = j%3;
    bf16x8 bfrag = *(const bf16x8*)(fbase + (dy*66 + dx)*64 + (kk & 1)*32 + g*8);
    bf16x8 afrag = *(const bf16x8*)(Wp + kk*32);
    acc = __builtin_amdgcn_mfma_f32_16x16x32_bf16(afrag, bfrag, acc, 0, 0, 0);
  }
  bf16x4 o4;
  o4[0] = (__bf16)acc[0]; o4[1] = (__bf16)acc[1];
  o4[2] = (__bf16)acc[2]; o4[3] = (__bf16)acc[3];
  if (nt < 16) *(bf16x4*)(coefB + gp*256 + nt*16 + g*4)        = o4;
  else         *(bf16x4*)(freqB + gp*256 + (nt - 16)*16 + g*4) = o4;
}

// ---------------- fused gather/fourier + 4-layer MLP + out layer ----------
// 256 threads (4 waves), 64 rows/block, 34 KiB LDS -> 4 blocks/CU.
// Wave tile 64q x 64n via 32x32x16 MFMA: LDS bytes/row halved vs R9;
// acc[2][2] f32x16 = 64 AGPR + VGPR<=64 keeps the 128-reg/4-wave budget.
__global__ __launch_bounds__(256, 4)
void mlp_kernel(const unsigned short* coefB, const unsigned short* freqB,
                const float* coord, const float* cell, const float* phase_w,
                const unsigned short* Wmlp,
                const float* b0, const float* b1, const float* b2, const float* b3,
                const unsigned short* wo_pad, const float* bo,
                float* areas, float* pred){
  __shared__ __align__(16) char Xs[64*256*2];    // 32 KiB swizzled bf16 [64][256]
  __shared__ __align__(16) float geo[4][16][8];  // 2 KiB row geometry
  int t = threadIdx.x;
  int r0 = blockIdx.x*64;
  int wave = t >> 6, lane = t & 63;
  int l16 = lane & 15, g = lane >> 4;
  int lr0 = wave*16;

  // ---- geometry: lane rr (<16) computes row lr0+rr ----
  if (lane < 16){
    int gr = r0 + lr0 + lane;
    int bq = gr >> 2, s = gr & 3;
    float2 crd = *(const float2*)(coord + bq*2);
    float2 cel = *(const float2*)(cell + bq*2);
    float vx = (s & 2) ? 1.f : -1.f;
    float vy = (s & 1) ? 1.f : -1.f;
    const float RX = 1.f/64.f;
    float cy = fminf(fmaxf(crd.x + vx*RX + 1e-6f, -1.f + 1e-6f), 1.f - 1e-6f);
    float cx = fminf(fmaxf(crd.y + vy*RX + 1e-6f, -1.f + 1e-6f), 1.f - 1e-6f);
    int iy = min(max((int)rintf((cy + 1.f)*32.f - 0.5f), 0), 63);
    int ix = min(max((int)rintf((cx + 1.f)*32.f - 0.5f), 0), 63);
    float qy = -1.f + (2*iy + 1)*RX;
    float qx = -1.f + (2*ix + 1)*RX;
    float rel0 = (crd.x - qy)*64.f;
    float rel1 = (crd.y - qx)*64.f;
    areas[gr] = fabsf(rel0*rel1) + 1e-9f;
    int b = gr >> 18;
    int pix = b*NPIX + iy*64 + ix;
    geo[wave][lane][0] = __int_as_float(pix);
    geo[wave][lane][1] = rel0;
    geo[wave][lane][2] = rel1;
    geo[wave][lane][3] = cel.x*64.f;
    geo[wave][lane][4] = cel.y*64.f;
  }
  // phase_w rows for this lane's 8 pairs (p = 8*l16 + e)
  float4 pw[4];
  #pragma unroll
  for (int j = 0; j < 4; j++)
    pw[j] = *(const float4*)(phase_w + 16*l16 + 4*j);
  __syncthreads();

  // ---- build X: 4 iterations x 4 concurrent rows (16 lanes per row) ----
  #pragma unroll
  for (int it = 0; it < 4; it++){
    int ri = it*4 + g;                    // row index within wave
    int lr = lr0 + ri;
    float4 g4 = *(const float4*)(&geo[wave][ri][0]);
    float ce1 = geo[wave][ri][4];
    int pix = __float_as_int(g4.x);
    float rel0 = g4.y, rel1 = g4.z, ce0 = g4.w;
    const unsigned short* fR = freqB + pix*256 + 16*l16;
    const unsigned short* cR = coefB + pix*256 + 8*l16;
    uint4 fva = *(const uint4*)(fR);       // freq elems 0..7  (pairs e=0..3)
    uint4 fvb = *(const uint4*)(fR + 8);   // freq elems 8..15 (pairs e=4..7)
    uint4 cca = *(const uint4*)(cR);       // coef cols 8*l16..+7
    uint4 csa = *(const uint4*)(cR + 128); // coef cols 128+8*l16..+7
    bf16x8 cv, sv;
    #pragma unroll
    for (int j = 0; j < 4; j++){
      unsigned uf0 = (j==0)?fva.x:(j==1)?fva.z:(j==2)?fvb.x:fvb.z;
      unsigned uf1 = (j==0)?fva.y:(j==1)?fva.w:(j==2)?fvb.y:fvb.w;
      unsigned uc  = (j==0)?cca.x:(j==1)?cca.y:(j==2)?cca.z:cca.w;
      unsigned us  = (j==0)?csa.x:(j==1)?csa.y:(j==2)?csa.z:csa.w;
      float2 f01 = bf2x(uf0);
      float2 f23 = bf2x(uf1);
      float2 cab = bf2x(uc);
      float2 sab = bf2x(us);
      float4 pj = pw[j];
      float q0 = f01.x*rel0 + f01.y*rel1 + ce0*pj.x + ce1*pj.y;
      float q1 = f23.x*rel0 + f23.y*rel1 + ce0*pj.z + ce1*pj.w;
      cv[2*j]   = (__bf16)(sin_rev(q0*0.5f + 0.25f) * cab.x);
      sv[2*j]   = (__bf16)(sin_rev(q0*0.5f)         * sab.x);
      cv[2*j+1] = (__bf16)(sin_rev(q1*0.5f + 0.25f) * cab.y);
      sv[2*j+1] = (__bf16)(sin_rev(q1*0.5f)         * sab.y);
    }
    *(bf16x8*)(Xs + xaddr(lr, 8*l16))       = cv;
    *(bf16x8*)(Xs + xaddr(lr, 128 + 8*l16)) = sv;
  }

  int l32 = lane & 31, h = lane >> 5;
  int n0 = wave*64;      // this wave owns output neurons n0..n0+63 each layer
  // preload layer-0 kk=0 W fragments (no Xs dependency; issues before barrier)
  bf16x8 wc0 = *(const bf16x8*)(Wmlp + (n0 +      l32)*256 + h*8);
  bf16x8 wc1 = *(const bf16x8*)(Wmlp + (n0 + 32 + l32)*256 + h*8);
  __syncthreads();

  const float* const bls[4] = {b0, b1, b2, b3};

  #pragma unroll
  for (int l = 0; l < 4; l++){
    const unsigned short* Wl = Wmlp + l*65536;
    const unsigned short* Wn = Wmlp + (l < 3 ? (l+1)*65536 : l*65536);
    f32x16 acc0A, acc0B, acc1A, acc1B;   // [qt][nt]: q-half x n-half
    #pragma unroll
    for (int nt = 0; nt < 2; nt++)
      #pragma unroll
      for (int rg = 0; rg < 4; rg++){
        float4 bv = *(const float4*)(bls[l] + n0 + nt*32 + rg*8 + h*4);
        #pragma unroll
        for (int j = 0; j < 4; j++){
          if (nt == 0){ acc0A[rg*4+j] = ((const float*)&bv)[j];
                        acc1A[rg*4+j] = ((const float*)&bv)[j]; }
          else        { acc0B[rg*4+j] = ((const float*)&bv)[j];
                        acc1B[rg*4+j] = ((const float*)&bv)[j]; }
        }
      }
    #pragma unroll
    for (int kk = 0; kk < 16; kk++){
      // prefetch next-kk (or next-layer kk0) W fragments
      bf16x8 wn0, wn1;
      if (kk < 15){
        wn0 = *(const bf16x8*)(Wl + (n0 +      l32)*256 + (kk+1)*16 + h*8);
        wn1 = *(const bf16x8*)(Wl + (n0 + 32 + l32)*256 + (kk+1)*16 + h*8);
      } else {
        wn0 = *(const bf16x8*)(Wn + (n0 +      l32)*256 + h*8);
        wn1 = *(const bf16x8*)(Wn + (n0 + 32 + l32)*256 + h*8);
      }
      bf16x8 xf0 = *(const bf16x8*)(Xs + xaddr(     l32, kk*16 + h*8));
      bf16x8 xf1 = *(const bf16x8*)(Xs + xaddr(32 + l32, kk*16 + h*8));
      acc0A = __builtin_amdgcn_mfma_f32_32x32x16_bf16(wc0, xf0, acc0A, 0,0,0);
      acc0B = __builtin_amdgcn_mfma_f32_32x32x16_bf16(wc1, xf0, acc0B, 0,0,0);
      acc1A = __builtin_amdgcn_mfma_f32_32x32x16_bf16(wc0, xf1, acc1A, 0,0,0);
      acc1B = __builtin_amdgcn_mfma_f32_32x32x16_bf16(wc1, xf1, acc1B, 0,0,0);
      wc0 = wn0; wc1 = wn1;
    }
    __syncthreads();   // all reads of Xs done -> safe to overwrite
    // D (32x32): col(query)=lane&31, row(neuron)=(reg&3)+8*(reg>>2)+4*h
    #pragma unroll
    for (int qt = 0; qt < 2; qt++){
      int row = qt*32 + l32;
      #pragma unroll
      for (int nt = 0; nt < 2; nt++)
        #pragma unroll
        for (int rg = 0; rg < 4; rg++){
          const f32x16& a = (qt==0) ? (nt==0 ? acc0A : acc0B)
                                    : (nt==0 ? acc1A : acc1B);
          int coln = n0 + nt*32 + rg*8 + h*4;
          bf16x4 u;
          u[0] = (__bf16)fmaxf(a[rg*4+0], 0.f);
          u[1] = (__bf16)fmaxf(a[rg*4+1], 0.f);
          u[2] = (__bf16)fmaxf(a[rg*4+2], 0.f);
          u[3] = (__bf16)fmaxf(a[rg*4+3], 0.f);
          *(bf16x4*)(Xs + xaddr(row, coln)) = u;
        }
    }
    __syncthreads();
  }

  // ---- output layer: A = wo_pad (16 padded rows), wave w -> 16 rows ----
  {
    f32x4 acc = {0.f, 0.f, 0.f, 0.f};
    #pragma unroll
    for (int kk = 0; kk < 8; kk++){
      bf16x8 wf = *(const bf16x8*)(wo_pad + l16*256 + kk*32 + g*8);
      bf16x8 xf = *(const bf16x8*)(Xs + xaddr(wave*16 + l16, kk*32 + g*8));
      acc = __builtin_amdgcn_mfma_f32_16x16x32_bf16(wf, xf, acc, 0, 0, 0);
    }
    if (g == 0){                         // channel = reg (0..3), xrow = l16
      int row = r0 + wave*16 + l16;
      pred[row*3 + 0] = acc[0] + bo[0];
      pred[row*3 + 1] = acc[1] + bo[1];
      pred[row*3 + 2] = acc[2] + bo[2];
    }
  }
}

// ---------------- combine: area blend + bilinear residual + BN partials ---
__global__ void combine_kernel(const float* pred, const float* areas,
                               const float* coord, const float* inp,
                               float* retbuf, float* partials){
  __shared__ float psum[8];
  int tid = threadIdx.x;
  if (tid < 8) psum[tid] = 0.f;
  __syncthreads();

  int bq = blockIdx.x*256 + tid;           // 0..131071
  int b  = bq >> 16;
  float4 ar = *(const float4*)(areas + bq*4);
  float tot = ar.x + ar.y + ar.z + ar.w;
  float w0_ = ar.w/tot, w1_ = ar.z/tot, w2_ = ar.y/tot, w3_ = ar.x/tot;
  const float* pp = pred + bq*12;
  float r_[3];
  #pragma unroll
  for (int c = 0; c < 3; c++)
    r_[c] = pp[c]*w0_ + pp[3+c]*w1_ + pp[6+c]*w2_ + pp[9+c]*w3_;

  float c0 = coord[bq*2], c1 = coord[bq*2+1];
  float fy = (c0 + 1.f)*32.f - 0.5f, fx = (c1 + 1.f)*32.f - 0.5f;
  float y0f = floorf(fy), x0f = floorf(fx);
  float wy = fy - y0f, wx = fx - x0f;
  int y0 = min(max((int)y0f, 0), 63), y1 = min(max((int)y0f + 1, 0), 63);
  int x0 = min(max((int)x0f, 0), 63), x1 = min(max((int)x0f + 1, 0), 63);
  const float* ib = inp + b*3*NPIX;
  #pragma unroll
  for (int c = 0; c < 3; c++){
    const float* pl = ib + c*NPIX;
    float v00 = pl[y0*64 + x0], v01 = pl[y0*64 + x1];
    float v10 = pl[y1*64 + x0], v11 = pl[y1*64 + x1];
    r_[c] += v00*(1.f-wy)*(1.f-wx) + v01*(1.f-wy)*wx
           + v10*wy*(1.f-wx)       + v11*wy*wx;
    retbuf[bq*3 + c] = r_[c];
  }
  #pragma unroll
  for (int c = 0; c < 3; c++){
    float s = r_[c], ss = r_[c]*r_[c];
    #pragma unroll
    for (int off = 32; off; off >>= 1){
      s  += __shfl_down(s,  off);
      ss += __shfl_down(ss, off);
    }
    if ((tid & 63) == 0){
      atomicAdd(&psum[c],     s);    // LDS atomics: 4 waves, no contention
      atomicAdd(&psum[4 + c], ss);
    }
  }
  __syncthreads();
  if (tid < 8) partials[blockIdx.x*8 + tid] = psum[tid];
}

// ---------------- reduce partials (512 blocks x 8 ch) -> bnsums -----------
__global__ void reduce_kernel(const float* partials, float* bnsums){
  int t = threadIdx.x;          // 512 threads
  int c = t >> 6;               // channel 0..7
  int i = t & 63;
  float s = 0.f;
  #pragma unroll
  for (int j = 0; j < 8; j++) s += partials[(i + 64*j)*8 + c];
  #pragma unroll
  for (int off = 32; off; off >>= 1) s += __shfl_down(s, off);
  if (i == 0) bnsums[c] = s;
}

// ---------------- batchnorm normalize -------------------------------------
__global__ void normalize_kernel(const float* retbuf, const float* bnsums,
                                 const float* gamma, const float* beta,
                                 float* out){
  int idx = blockIdx.x*256 + threadIdx.x;
  if (idx >= BQ*QQ*3) return;
  int c = idx % 3;
  const float n = (float)(BQ*QQ);
  float mean = bnsums[c] / n;
  float var  = bnsums[4 + c] / n - mean*mean;
  out[idx] = (retbuf[idx] - mean) * rsqrtf(var + 1e-5f) * gamma[c] + beta[c];
}

extern "C" void kernel_launch(void* const* d_in, const int* in_sizes, int n_in,
                              void* d_out, int out_size, void* d_ws, size_t ws_size,
                              hipStream_t stream){
  const float* inp    = (const float*)d_in[0];
  const float* coord  = (const float*)d_in[1];
  const float* cell   = (const float*)d_in[2];
  const float* enc_w  = (const float*)d_in[3];
  const float* enc_b  = (const float*)d_in[4];
  const float* coef_w = (const float*)d_in[5];
  const float* coef_b = (const float*)d_in[6];
  const float* freq_w = (const float*)d_in[7];
  const float* freq_b = (const float*)d_in[8];
  const float* phase_w= (const float*)d_in[9];
  const float* w0 = (const float*)d_in[10]; const float* b0 = (const float*)d_in[11];
  const float* w1 = (const float*)d_in[12]; const float* b1 = (const float*)d_in[13];
  const float* w2 = (const float*)d_in[14]; const float* b2 = (const float*)d_in[15];
  const float* w3 = (const float*)d_in[16]; const float* b3 = (const float*)d_in[17];
  const float* wo = (const float*)d_in[18]; const float* bo = (const float*)d_in[19];
  const float* gamma = (const float*)d_in[20]; const float* beta = (const float*)d_in[21];

  char* ws = (char*)d_ws;
  unsigned short* fpad   = (unsigned short*)(ws + 0);          // 1,115,136 B
  unsigned short* coefB  = (unsigned short*)(ws + 1116160);    // 4 MB bf16
  unsigned short* freqB  = (unsigned short*)(ws + 5310464);    // 4 MB bf16
  unsigned short* Wcat   = (unsigned short*)(ws + 9504768);    // 576 KB
  unsigned short* Wmlp   = (unsigned short*)(ws + 10094592);   // 512 KB
  unsigned short* wo_pad = (unsigned short*)(ws + 10618880);   // 8 KB
  float*          areas  = (float*)(ws + 10627072);            // 2 MB
  float*          pred   = (float*)(ws + 12724224);            // 6 MB
  float*          retbuf = (float*)(ws + 19015680);            // 1.5 MB
  float*          partials=(float*)(ws + 20588544);            // 16 KB
  float*          bnsums = (float*)(ws + 20604928);            // 32 B
  if (ws_size < 20604960) return;

  hipMemsetAsync(fpad, 0, 1115136, stream);       // zero border
  prep_kernel<<<2192, 256, 0, stream>>>(coef_w, freq_w, w0, w1, w2, w3, wo,
                                        Wcat, Wmlp, wo_pad);
  enc_conv_kernel<<<256, 256, 0, stream>>>(inp, enc_w, enc_b, fpad);
  conv_gemm_kernel<<<4096, 256, 0, stream>>>(fpad, Wcat, coef_b, freq_b,
                                             coefB, freqB);
  mlp_kernel<<<8192, 256, 0, stream>>>(coefB, freqB, coord, cell, phase_w, Wmlp,
                                       b0, b1, b2, b3, wo_pad, bo, areas, pred);
  combine_kernel<<<512, 256, 0, stream>>>(pred, areas, coord, inp, retbuf,
                                          partials);
  reduce_kernel<<<1, 512, 0, stream>>>(partials, bnsums);
  normalize_kernel<<<1536, 256, 0, stream>>>(retbuf, bnsums, gamma, beta,
                                             (float*)d_out);
}

// Round 13
// 405.091 us; speedup vs baseline: 1.6151x; 1.6151x over previous
//
#include <hip/hip_runtime.h>

#define BQ   2
#define QQ   65536
#define HID  256
#define ENC  64
#define NPIX 4096          // 64*64
#define KCONV 576          // ENC*9
#define NROW (BQ*QQ*4)     // 524288

using bf16x8 = __bf16 __attribute__((ext_vector_type(8)));
using bf16x4 = __bf16 __attribute__((ext_vector_type(4)));
using f32x4  = float  __attribute__((ext_vector_type(4)));

__device__ __forceinline__ unsigned short f2bf(float f){
  unsigned u = __float_as_uint(f);
  u = (u + 0x7fffu + ((u >> 16) & 1u)) >> 16;
  return (unsigned short)u;
}
// unpack 2 packed bf16 (one uint) -> 2 floats (low ushort = first elem)
__device__ __forceinline__ float2 bf2x(unsigned u){
  float2 r;
  r.x = __uint_as_float(u << 16);
  r.y = __uint_as_float(u & 0xffff0000u);
  return r;
}

// sin(2*pi*r) via v_fract + v_sin (ISA: v_sin input in revolutions).
__device__ __forceinline__ float sin_rev(float r){
  float f, s;
  asm("v_fract_f32 %0, %1" : "=v"(f) : "v"(r));
  asm("v_sin_f32 %0, %1"   : "=v"(s) : "v"(f));
  return s;
}

// byte offset of bf16 element (row,col) in a [128][256] bf16 LDS tile,
// XOR-swizzled at 16B granularity (R4-validated; hand-audited bank-balanced
// for all three access patterns: xf b128 reads, build b128 writes, epi b64).
__device__ __forceinline__ int xaddr(int row, int col){
  return row*512 + ((((col >> 3) ^ (row & 7)) << 4) | ((col & 7) << 1));
}

// ---------------- fused prep (weights) + enc conv -------------------------
// blocks 0..2191: weight conversion; blocks 2192..2447: 3x3 enc conv.
// Independent outputs -> safe to run concurrently in one dispatch.
__global__ __launch_bounds__(256)
void prep_enc_kernel(const float* coef_w, const float* freq_w,
                     const float* w0, const float* w1,
                     const float* w2, const float* w3,
                     const float* wo, const float* inp,
                     const float* enc_w, const float* enc_b,
                     unsigned short* Wcat, unsigned short* Wmlp,
                     unsigned short* wo_pad, unsigned short* fpad){
  __shared__ float wl[ENC*27];
  __shared__ float bl2[ENC];
  int t = threadIdx.x;
  if (blockIdx.x < 2192){
    int idx = blockIdx.x*256 + t;
    if (idx < 512*KCONV){
      int n = idx / KCONV, k = idx % KCONV;
      int j = k >> 6, cin = k & 63;
      const float* src = (n < 256) ? coef_w : freq_w;
      Wcat[idx] = f2bf(src[(n & 255)*KCONV + cin*9 + j]);
      return;
    }
    int i2 = idx - 512*KCONV;
    if (i2 < 4*65536){
      const float* wl_ = (i2 < 65536) ? w0 : (i2 < 131072) ? w1
                       : (i2 < 196608) ? w2 : w3;
      Wmlp[i2] = f2bf(wl_[i2 & 65535]);
      return;
    }
    int i3 = i2 - 4*65536;
    if (i3 < 16*256){
      int c = i3 >> 8, k = i3 & 255;
      wo_pad[i3] = (c < 3) ? f2bf(wo[c*256 + k]) : (unsigned short)0;
    }
    return;
  }
  // ---- enc conv: 32 px/block, 8 threads/pixel, 8 channels/thread ----
  for (int i = t; i < ENC*27; i += 256) wl[i] = enc_w[i];
  if (t < ENC) bl2[t] = enc_b[t];
  __syncthreads();
  int px  = (blockIdx.x - 2192)*32 + (t >> 3);   // 0..8191
  int oc0 = (t & 7)*8;
  int b = px >> 12, yx = px & 4095;
  int y = yx >> 6, x = yx & 63;
  float v[27];
  #pragma unroll
  for (int c = 0; c < 3; c++)
    #pragma unroll
    for (int dy = 0; dy < 3; dy++)
      #pragma unroll
      for (int dx = 0; dx < 3; dx++){
        int yy = y + dy - 1, xx = x + dx - 1;
        v[c*9 + dy*3 + dx] = (yy >= 0 && yy < 64 && xx >= 0 && xx < 64)
                             ? inp[(b*3 + c)*NPIX + yy*64 + xx] : 0.f;
      }
  bf16x8 o;
  #pragma unroll
  for (int oc = 0; oc < 8; oc++){
    float acc = bl2[oc0 + oc];
    #pragma unroll
    for (int k = 0; k < 27; k++) acc += wl[(oc0 + oc)*27 + k]*v[k];
    o[oc] = (__bf16)acc;
  }
  *(bf16x8*)(fpad + ((b*66 + y + 1)*66 + x + 1)*64 + oc0) = o;
}

// ---------------- conv GEMM: coef/freq -> bf16 pixel-major -----------------
__global__ __launch_bounds__(256)
void conv_gemm_kernel(const unsigned short* fpad, const unsigned short* Wcat,
                      const float* coef_b, const float* freq_b,
                      unsigned short* coefB, unsigned short* freqB){
  int wave = threadIdx.x >> 6, lane = threadIdx.x & 63;
  int l16 = lane & 15, g = lane >> 4;
  int tile = blockIdx.x*4 + wave;           // 16384 = 512 pt * 32 nt
  int nt = tile & 31, pt = tile >> 5;
  int gp = pt*16 + l16;                     // pixel handled by this lane
  int b = gp >> 12, y = (gp >> 6) & 63, x = gp & 63;
  const unsigned short* fbase = fpad + ((b*66 + y)*66 + x)*64;
  const unsigned short* Wp = Wcat + (nt*16 + l16)*KCONV + g*8;
  f32x4 acc;
  {
    const float* bsrc = (nt < 16) ? coef_b : freq_b;
    float4 b4 = *(const float4*)(bsrc + ((nt*16) & 255) + g*4);
    acc[0] = b4.x; acc[1] = b4.y; acc[2] = b4.z; acc[3] = b4.w;
  }
  #pragma unroll
  for (int kk = 0; kk < 18; kk++){
    int j = kk >> 1, dy = j/3, dx = j%3;
    bf16x8 bfrag = *(const bf16x8*)(fbase + (dy*66 + dx)*64 + (kk & 1)*32 + g*8);
    bf16x8 afrag = *(const bf16x8*)(Wp + kk*32);
    acc = __builtin_amdgcn_mfma_f32_16x16x32_bf16(afrag, bfrag, acc, 0, 0, 0);
  }
  bf16x4 o4;
  o4[0] = (__bf16)acc[0]; o4[1] = (__bf16)acc[1];
  o4[2] = (__bf16)acc[2]; o4[3] = (__bf16)acc[3];
  if (nt < 16) *(bf16x4*)(coefB + gp*256 + nt*16 + g*4)        = o4;
  else         *(bf16x4*)(freqB + gp*256 + (nt - 16)*16 + g*4) = o4;
}

// ---------------- fused gather/fourier + 4-layer MLP + out layer ----------
// R11 mlp, unchanged: 512 thr (8 waves), 128 rows/block, 68 KiB LDS,
// 2 blocks/CU, N=8 split (W read once per block-layer), 2-deep W prefetch.
__global__ __launch_bounds__(512, 4)
void mlp_kernel(const unsigned short* coefB, const unsigned short* freqB,
                const float* coord, const float* cell, const float* phase_w,
                const unsigned short* Wmlp,
                const float* b0, const float* b1, const float* b2, const float* b3,
                const unsigned short* wo_pad, const float* bo,
                float* areas, float* pred){
  __shared__ __align__(16) char Xs[128*256*2];   // 64 KiB swizzled bf16 [128][256]
  __shared__ __align__(16) float geo[8][16][8];  // 4 KiB row geometry
  int t = threadIdx.x;
  int r0 = blockIdx.x*128;
  int wave = t >> 6, lane = t & 63;
  int l16 = lane & 15, g = lane >> 4;
  int lr0 = wave*16;

  // ---- geometry: lane rr (<16) computes row lr0+rr ----
  if (lane < 16){
    int gr = r0 + lr0 + lane;
    int bq = gr >> 2, s = gr & 3;
    float2 crd = *(const float2*)(coord + bq*2);
    float2 cel = *(const float2*)(cell + bq*2);
    float vx = (s & 2) ? 1.f : -1.f;
    float vy = (s & 1) ? 1.f : -1.f;
    const float RX = 1.f/64.f;
    float cy = fminf(fmaxf(crd.x + vx*RX + 1e-6f, -1.f + 1e-6f), 1.f - 1e-6f);
    float cx = fminf(fmaxf(crd.y + vy*RX + 1e-6f, -1.f + 1e-6f), 1.f - 1e-6f);
    int iy = min(max((int)rintf((cy + 1.f)*32.f - 0.5f), 0), 63);
    int ix = min(max((int)rintf((cx + 1.f)*32.f - 0.5f), 0), 63);
    float qy = -1.f + (2*iy + 1)*RX;
    float qx = -1.f + (2*ix + 1)*RX;
    float rel0 = (crd.x - qy)*64.f;
    float rel1 = (crd.y - qx)*64.f;
    areas[gr] = fabsf(rel0*rel1) + 1e-9f;
    int b = gr >> 18;
    int pix = b*NPIX + iy*64 + ix;
    geo[wave][lane][0] = __int_as_float(pix);
    geo[wave][lane][1] = rel0;
    geo[wave][lane][2] = rel1;
    geo[wave][lane][3] = cel.x*64.f;
    geo[wave][lane][4] = cel.y*64.f;
  }
  // phase_w rows for this lane's 8 pairs (p = 8*l16 + e)
  float4 pw[4];
  #pragma unroll
  for (int j = 0; j < 4; j++)
    pw[j] = *(const float4*)(phase_w + 16*l16 + 4*j);
  __syncthreads();

  // ---- build X: 4 iterations x 4 concurrent rows (16 lanes per row) ----
  #pragma unroll
  for (int it = 0; it < 4; it++){
    int ri = it*4 + g;                    // row index within wave
    int lr = lr0 + ri;
    float4 g4 = *(const float4*)(&geo[wave][ri][0]);
    float ce1 = geo[wave][ri][4];
    int pix = __float_as_int(g4.x);
    float rel0 = g4.y, rel1 = g4.z, ce0 = g4.w;
    const unsigned short* fR = freqB + pix*256 + 16*l16;
    const unsigned short* cR = coefB + pix*256 + 8*l16;
    uint4 fva = *(const uint4*)(fR);       // freq elems 0..7  (pairs e=0..3)
    uint4 fvb = *(const uint4*)(fR + 8);   // freq elems 8..15 (pairs e=4..7)
    uint4 cca = *(const uint4*)(cR);       // coef cols 8*l16..+7
    uint4 csa = *(const uint4*)(cR + 128); // coef cols 128+8*l16..+7
    bf16x8 cv, sv;
    #pragma unroll
    for (int j = 0; j < 4; j++){
      unsigned uf0 = (j==0)?fva.x:(j==1)?fva.z:(j==2)?fvb.x:fvb.z;
      unsigned uf1 = (j==0)?fva.y:(j==1)?fva.w:(j==2)?fvb.y:fvb.w;
      unsigned uc  = (j==0)?cca.x:(j==1)?cca.y:(j==2)?cca.z:cca.w;
      unsigned us  = (j==0)?csa.x:(j==1)?csa.y:(j==2)?csa.z:csa.w;
      float2 f01 = bf2x(uf0);
      float2 f23 = bf2x(uf1);
      float2 cab = bf2x(uc);
      float2 sab = bf2x(us);
      float4 pj = pw[j];
      float q0 = f01.x*rel0 + f01.y*rel1 + ce0*pj.x + ce1*pj.y;
      float q1 = f23.x*rel0 + f23.y*rel1 + ce0*pj.z + ce1*pj.w;
      cv[2*j]   = (__bf16)(sin_rev(q0*0.5f + 0.25f) * cab.x);
      sv[2*j]   = (__bf16)(sin_rev(q0*0.5f)         * sab.x);
      cv[2*j+1] = (__bf16)(sin_rev(q1*0.5f + 0.25f) * cab.y);
      sv[2*j+1] = (__bf16)(sin_rev(q1*0.5f)         * sab.y);
    }
    *(bf16x8*)(Xs + xaddr(lr, 8*l16))       = cv;
    *(bf16x8*)(Xs + xaddr(lr, 128 + 8*l16)) = sv;
  }

  int n0 = wave*32;      // this wave owns output neurons n0..n0+31 each layer
  // preload layer-0 kk=0 W fragments (no Xs dependency; issues before barrier)
  bf16x8 wf0c = *(const bf16x8*)(Wmlp + (n0 + l16)*256      + g*8);
  bf16x8 wf1c = *(const bf16x8*)(Wmlp + (n0 + 16 + l16)*256 + g*8);
  __syncthreads();

  const float* const bls[4] = {b0, b1, b2, b3};

  #pragma unroll
  for (int l = 0; l < 4; l++){
    const unsigned short* Wl = Wmlp + l*65536;
    const unsigned short* Wn = Wmlp + (l < 3 ? (l+1)*65536 : l*65536);
    f32x4 acc[8][2];
    #pragma unroll
    for (int nt = 0; nt < 2; nt++){
      float4 bv = *(const float4*)(bls[l] + n0 + nt*16 + g*4);
      #pragma unroll
      for (int rt = 0; rt < 8; rt++){
        acc[rt][nt][0] = bv.x; acc[rt][nt][1] = bv.y;
        acc[rt][nt][2] = bv.z; acc[rt][nt][3] = bv.w;
      }
    }
    #pragma unroll
    for (int kk = 0; kk < 8; kk++){
      // prefetch next-kk (or next-layer kk0) W fragments
      bf16x8 wf0n, wf1n;
      if (kk < 7){
        wf0n = *(const bf16x8*)(Wl + (n0 + l16)*256      + (kk+1)*32 + g*8);
        wf1n = *(const bf16x8*)(Wl + (n0 + 16 + l16)*256 + (kk+1)*32 + g*8);
      } else {
        wf0n = *(const bf16x8*)(Wn + (n0 + l16)*256      + g*8);
        wf1n = *(const bf16x8*)(Wn + (n0 + 16 + l16)*256 + g*8);
      }
      #pragma unroll
      for (int rt = 0; rt < 8; rt++){
        bf16x8 xf = *(const bf16x8*)(Xs + xaddr(rt*16 + l16, kk*32 + g*8));
        acc[rt][0] = __builtin_amdgcn_mfma_f32_16x16x32_bf16(wf0c, xf, acc[rt][0], 0,0,0);
        acc[rt][1] = __builtin_amdgcn_mfma_f32_16x16x32_bf16(wf1c, xf, acc[rt][1], 0,0,0);
      }
      wf0c = wf0n; wf1c = wf1n;
    }
    __syncthreads();   // all reads of Xs done -> safe to overwrite
    // D: row(neuron)=g*4+r, col(xrow)=l16 -> packed bf16x4 per (rt,nt)
    #pragma unroll
    for (int rt = 0; rt < 8; rt++)
      #pragma unroll
      for (int nt = 0; nt < 2; nt++){
        int row = rt*16 + l16;
        int col = n0 + nt*16 + g*4;
        bf16x4 u;
        u[0] = (__bf16)fmaxf(acc[rt][nt][0], 0.f);
        u[1] = (__bf16)fmaxf(acc[rt][nt][1], 0.f);
        u[2] = (__bf16)fmaxf(acc[rt][nt][2], 0.f);
        u[3] = (__bf16)fmaxf(acc[rt][nt][3], 0.f);
        *(bf16x4*)(Xs + xaddr(row, col)) = u;
      }
    __syncthreads();
  }

  // ---- output layer: A = wo_pad (16 padded rows), wave w -> 16 rows ----
  {
    f32x4 acc = {0.f, 0.f, 0.f, 0.f};
    #pragma unroll
    for (int kk = 0; kk < 8; kk++){
      bf16x8 wf = *(const bf16x8*)(wo_pad + l16*256 + kk*32 + g*8);
      bf16x8 xf = *(const bf16x8*)(Xs + xaddr(wave*16 + l16, kk*32 + g*8));
      acc = __builtin_amdgcn_mfma_f32_16x16x32_bf16(wf, xf, acc, 0, 0, 0);
    }
    if (g == 0){                         // channel = reg (0..3), xrow = l16
      int row = r0 + wave*16 + l16;
      pred[row*3 + 0] = acc[0] + bo[0];
      pred[row*3 + 1] = acc[1] + bo[1];
      pred[row*3 + 2] = acc[2] + bo[2];
    }
  }
}

// ---------------- combine: area blend + bilinear residual + BN partials ---
__global__ void combine_kernel(const float* pred, const float* areas,
                               const float* coord, const float* inp,
                               float* retbuf, float* partials){
  __shared__ float psum[8];
  int tid = threadIdx.x;
  if (tid < 8) psum[tid] = 0.f;
  __syncthreads();

  int bq = blockIdx.x*256 + tid;           // 0..131071
  int b  = bq >> 16;
  float4 ar = *(const float4*)(areas + bq*4);
  float tot = ar.x + ar.y + ar.z + ar.w;
  float w0_ = ar.w/tot, w1_ = ar.z/tot, w2_ = ar.y/tot, w3_ = ar.x/tot;
  const float* pp = pred + bq*12;
  float r_[3];
  #pragma unroll
  for (int c = 0; c < 3; c++)
    r_[c] = pp[c]*w0_ + pp[3+c]*w1_ + pp[6+c]*w2_ + pp[9+c]*w3_;

  float c0 = coord[bq*2], c1 = coord[bq*2+1];
  float fy = (c0 + 1.f)*32.f - 0.5f, fx = (c1 + 1.f)*32.f - 0.5f;
  float y0f = floorf(fy), x0f = floorf(fx);
  float wy = fy - y0f, wx = fx - x0f;
  int y0 = min(max((int)y0f, 0), 63), y1 = min(max((int)y0f + 1, 0), 63);
  int x0 = min(max((int)x0f, 0), 63), x1 = min(max((int)x0f + 1, 0), 63);
  const float* ib = inp + b*3*NPIX;
  #pragma unroll
  for (int c = 0; c < 3; c++){
    const float* pl = ib + c*NPIX;
    float v00 = pl[y0*64 + x0], v01 = pl[y0*64 + x1];
    float v10 = pl[y1*64 + x0], v11 = pl[y1*64 + x1];
    r_[c] += v00*(1.f-wy)*(1.f-wx) + v01*(1.f-wy)*wx
           + v10*wy*(1.f-wx)       + v11*wy*wx;
    retbuf[bq*3 + c] = r_[c];
  }
  #pragma unroll
  for (int c = 0; c < 3; c++){
    float s = r_[c], ss = r_[c]*r_[c];
    #pragma unroll
    for (int off = 32; off; off >>= 1){
      s  += __shfl_down(s,  off);
      ss += __shfl_down(ss, off);
    }
    if ((tid & 63) == 0){
      atomicAdd(&psum[c],     s);    // LDS atomics: 4 waves, no contention
      atomicAdd(&psum[4 + c], ss);
    }
  }
  __syncthreads();
  if (tid < 8) partials[blockIdx.x*8 + tid] = psum[tid];
}

// ---------------- normalize (folds the partials reduction in) -------------
__global__ __launch_bounds__(256)
void normalize_kernel(const float* retbuf, const float* partials,
                      const float* gamma, const float* beta, float* out){
  __shared__ float sm[32][8];
  __shared__ float bns[8];
  int t = threadIdx.x;
  // per-block reduce of 512x8 partials: 256 threads, c = t&7, i = t>>3 (32)
  {
    int c = t & 7, i = t >> 3;
    float s = 0.f;
    #pragma unroll
    for (int j = 0; j < 16; j++) s += partials[(i + 32*j)*8 + c];
    sm[i][c] = s;
  }
  __syncthreads();
  if (t < 8){
    float s = 0.f;
    #pragma unroll
    for (int i = 0; i < 32; i++) s += sm[i][t];
    bns[t] = s;
  }
  __syncthreads();
  const float n = (float)(BQ*QQ);
  float mean[3], scal[3];
  #pragma unroll
  for (int c = 0; c < 3; c++){
    mean[c] = bns[c] / n;
    float var = bns[4 + c] / n - mean[c]*mean[c];
    scal[c] = rsqrtf(var + 1e-5f) * gamma[c];
  }
  int idx = blockIdx.x*256 + t;
  if (idx >= BQ*QQ*3) return;
  int c = idx % 3;
  out[idx] = (retbuf[idx] - mean[c]) * scal[c] + beta[c];
}

extern "C" void kernel_launch(void* const* d_in, const int* in_sizes, int n_in,
                              void* d_out, int out_size, void* d_ws, size_t ws_size,
                              hipStream_t stream){
  const float* inp    = (const float*)d_in[0];
  const float* coord  = (const float*)d_in[1];
  const float* cell   = (const float*)d_in[2];
  const float* enc_w  = (const float*)d_in[3];
  const float* enc_b  = (const float*)d_in[4];
  const float* coef_w = (const float*)d_in[5];
  const float* coef_b = (const float*)d_in[6];
  const float* freq_w = (const float*)d_in[7];
  const float* freq_b = (const float*)d_in[8];
  const float* phase_w= (const float*)d_in[9];
  const float* w0 = (const float*)d_in[10]; const float* b0 = (const float*)d_in[11];
  const float* w1 = (const float*)d_in[12]; const float* b1 = (const float*)d_in[13];
  const float* w2 = (const float*)d_in[14]; const float* b2 = (const float*)d_in[15];
  const float* w3 = (const float*)d_in[16]; const float* b3 = (const float*)d_in[17];
  const float* wo = (const float*)d_in[18]; const float* bo = (const float*)d_in[19];
  const float* gamma = (const float*)d_in[20]; const float* beta = (const float*)d_in[21];

  char* ws = (char*)d_ws;
  unsigned short* fpad   = (unsigned short*)(ws + 0);          // 1,115,136 B
  unsigned short* coefB  = (unsigned short*)(ws + 1116160);    // 4 MB bf16
  unsigned short* freqB  = (unsigned short*)(ws + 5310464);    // 4 MB bf16
  unsigned short* Wcat   = (unsigned short*)(ws + 9504768);    // 576 KB
  unsigned short* Wmlp   = (unsigned short*)(ws + 10094592);   // 512 KB
  unsigned short* wo_pad = (unsigned short*)(ws + 10618880);   // 8 KB
  float*          areas  = (float*)(ws + 10627072);            // 2 MB
  float*          pred   = (float*)(ws + 12724224);            // 6 MB
  float*          retbuf = (float*)(ws + 19015680);            // 1.5 MB
  float*          partials=(float*)(ws + 20588544);            // 16 KB
  if (ws_size < 20604960) return;

  hipMemsetAsync(fpad, 0, 1115136, stream);       // zero border
  prep_enc_kernel<<<2448, 256, 0, stream>>>(coef_w, freq_w, w0, w1, w2, w3, wo,
                                            inp, enc_w, enc_b,
                                            Wcat, Wmlp, wo_pad, fpad);
  conv_gemm_kernel<<<4096, 256, 0, stream>>>(fpad, Wcat, coef_b, freq_b,
                                             coefB, freqB);
  mlp_kernel<<<4096, 512, 0, stream>>>(coefB, freqB, coord, cell, phase_w, Wmlp,
                                       b0, b1, b2, b3, wo_pad, bo, areas, pred);
  combine_kernel<<<512, 256, 0, stream>>>(pred, areas, coord, inp, retbuf,
                                          partials);
  normalize_kernel<<<1536, 256, 0, stream>>>(retbuf, partials, gamma, beta,
                                             (float*)d_out);
}